// Round 5
// baseline (292.773 us; speedup 1.0000x reference)
//
#include <hip/hip_runtime.h>
#include <hip/hip_bf16.h>
#include <stdint.h>

#define B_ 4
#define S_ 2048
#define E_ 1024

// Session ledger:
//  R1/R2: 8-phase 256^2 port — correct but ~80us/25% MfmaUtil (worse than
//    2-barrier 75us/28%). Theory: hipcc inserts conservative vmcnt drains
//    before each phase's ds_reads (can't prove global_load_lds no-alias).
//    PARKED permanently (2 strikes, no disasm access in loop).
//  R3: revert + memset-fusion = baseline 256.5us. Anchor.
//  R4: PV BN=64 + compact Q/K = 262.1 (BN=64 doubled Sc re-reads). Reverted.
//    Counter re-read: top-5 rows are all QKV (2 rocprof passes); derived
//    timings: cvt~13, QKV~77 (673 TF, structure ceiling), scores~95-100,
//    PV~55-65, gaps~8.
//  R5 (this): round-3 config + split-K=2 for PV only (512->1024 blocks,
//    2->4 blocks/CU; PV was the only dispatch below 4/CU). out pre-zeroed,
//    PV epilogue atomicAdd of (P.V)/rowsum (linear => exact).

typedef __bf16 bf16;
typedef __attribute__((ext_vector_type(8))) __bf16 bf16x8;
typedef __attribute__((ext_vector_type(4))) float f32x4;
typedef __attribute__((ext_vector_type(4))) float float4v;
typedef __attribute__((ext_vector_type(4))) unsigned int uint4v;
typedef __attribute__((ext_vector_type(4))) unsigned short ushort4v;

__device__ inline unsigned short f2bf(float f) {
  union { float f; unsigned int u; } c; c.f = f;
  unsigned int u = c.u;
  unsigned int r = (u + 0x7FFFu + ((u >> 16) & 1u)) >> 16;
  return (unsigned short)r;
}

__device__ inline void load16_to_lds(const void* g, void* l) {
  __builtin_amdgcn_global_load_lds(
      (const __attribute__((address_space(1))) void*)g,
      (__attribute__((address_space(3))) void*)l,
      16, 0, 0);
}

// ---------------------------------------------------------------------------
// Merged fp32->bf16 converter: x (8192 blocks) + 3 weights (1024 each) +
// rowsum zeroing (8 blocks).
// ---------------------------------------------------------------------------
__global__ __launch_bounds__(256) void cvt_all(
    const float* __restrict__ x, const float* __restrict__ w0,
    const float* __restrict__ w1, const float* __restrict__ w2,
    unsigned short* __restrict__ out, float* __restrict__ rowsum) {
  if (blockIdx.x >= 11264) {  // 8 blocks: zero rowsum[8192] (fp32)
    rowsum[(blockIdx.x - 11264) * 256 + threadIdx.x] = 0.f;
    return;
  }
  const long off = (long)blockIdx.x * 256 + threadIdx.x;  // float4 units
  const float* in;
  long ibase;
  if (blockIdx.x < 8192)       { in = x;  ibase = 0; }
  else if (blockIdx.x < 9216)  { in = w0; ibase = 8192L * 256; }
  else if (blockIdx.x < 10240) { in = w1; ibase = 9216L * 256; }
  else                         { in = w2; ibase = 10240L * 256; }
  float4v f = ((const float4v*)in)[off - ibase];
  ushort4v o;
  o.x = f2bf(f.x); o.y = f2bf(f.y); o.z = f2bf(f.z); o.w = f2bf(f.w);
  ((ushort4v*)out)[off] = o;
}

// ---------------------------------------------------------------------------
// bt-GEMM: C[m][n] = sum_k A[m][k] * B[n][k]   [proven K-loop, unchanged]
// SWZ 0: (x,y,z) = blockIdx      SWZ 1: 1D grid, XCD-pinned batches.
// KSPLIT 2 (MODE 8 only): K halved per block, kh from grid, atomicAdd out.
// MODE 6: fused QKV projection epilogue (QK rows + transposed V)
// MODE 7: scores: write exp(acc*scale) bf16 + atomic fp32 row-sums
// MODE 8: PV: fp32 out (atomicAdd when split), divided by rowsum[row]
// ---------------------------------------------------------------------------
template <int MODE, int SWZ, int NXT, int KSPLIT>
__global__ __launch_bounds__(256, 4) void gemm_bt(
    const bf16* __restrict__ A, const bf16* __restrict__ B, void* __restrict__ Cv,
    const float* __restrict__ bias, const float* __restrict__ bias_b,
    const float* __restrict__ bias_v, unsigned short* __restrict__ VtOut,
    float* __restrict__ rowsum,
    int M, int N, int K, int lda, int ldb, int ldc,
    long sA, long sB, long sC, float scale, int nyt) {
  __shared__ bf16 As[128 * 64];
  __shared__ bf16 Bs[128 * 64];

  int xt, yt, zb, kh = 0;
  if (SWZ == 0) {
    xt = blockIdx.x; yt = blockIdx.y; zb = blockIdx.z;
  } else {  // SWZ == 1
    const int flat = blockIdx.x;
    const int xcd = flat & 7;
    int local = flat >> 3;
    if (KSPLIT == 2) { kh = local & 1; local >>= 1; }
    zb = xcd >> 1;
    const int w = (xcd & 1) * (NXT * nyt / 2) + local;
    xt = w % NXT; yt = w / NXT;
  }

  A += (long)zb * sA;
  B += (long)zb * sB;
  const int tid = threadIdx.x;
  const int wave = tid >> 6;
  const int lane = tid & 63;
  const int lrow = lane & 15;
  const int quad = lane >> 4;
  const int row0 = yt * 128;
  const int col0 = xt * 128;
  const int wm = (wave >> 1) * 64;
  const int wn = (wave & 1) * 64;

  f32x4 acc[4][4] = {};

  // staging geometry: r0 in [0,32), c0 in {0,8,...,56}; rows r0+32i
  const int r0 = wave * 8 + (lane >> 3);
  const int c0 = (lane & 7) * 8;

  const int K2 = K / KSPLIT;
  const int kbase = kh * K2;

  const bf16* pA0 = A + (long)(row0 + r0) * lda + c0 + kbase;
  const bf16* pA1 = pA0 + 32L * lda;
  const bf16* pA2 = pA0 + 64L * lda;
  const bf16* pA3 = pA0 + 96L * lda;
  const bf16* pB0 = B + (long)(col0 + r0) * ldb + c0 + kbase;
  const bf16* pB1 = pB0 + 32L * ldb;
  const bf16* pB2 = pB0 + 64L * ldb;
  const bf16* pB3 = pB0 + 96L * ldb;
  bf16* ldsA = As + wave * 512;  // wave-uniform; HW scatters lane*16B
  bf16* ldsB = Bs + wave * 512;

  for (int ks = 0; ks < K2; ks += 64) {
    load16_to_lds(pA0, ldsA);
    load16_to_lds(pA1, ldsA + 2048);
    load16_to_lds(pA2, ldsA + 4096);
    load16_to_lds(pA3, ldsA + 6144);
    load16_to_lds(pB0, ldsB);
    load16_to_lds(pB1, ldsB + 2048);
    load16_to_lds(pB2, ldsB + 4096);
    load16_to_lds(pB3, ldsB + 6144);
    __syncthreads();
#pragma unroll
    for (int kk = 0; kk < 64; kk += 32) {
      bf16x8 af[4], bfr[4];
#pragma unroll
      for (int i = 0; i < 4; ++i)
        af[i] = *(const bf16x8*)(As + (wm + i * 16 + lrow) * 64 + kk + quad * 8);
#pragma unroll
      for (int j = 0; j < 4; ++j)
        bfr[j] = *(const bf16x8*)(Bs + (wn + j * 16 + lrow) * 64 + kk + quad * 8);
#pragma unroll
      for (int i = 0; i < 4; ++i)
#pragma unroll
        for (int j = 0; j < 4; ++j)
          acc[i][j] = __builtin_amdgcn_mfma_f32_16x16x32_bf16(af[i], bfr[j], acc[i][j], 0, 0, 0);
    }
    __syncthreads();
    pA0 += 64; pA1 += 64; pA2 += 64; pA3 += 64;
    pB0 += 64; pB1 += 64; pB2 += 64; pB3 += 64;
  }

  // epilogue: D mapping (verified m89/m91): row = quad*4 + r (m), col = lrow (n)
  if (MODE == 8) {
    // PV: fp32 out, scaled by 1/rowsum[row] (rowsum L2-hot, 32 KB).
    // KSPLIT=2: out pre-zeroed; per-half division is exact (linear in P).
    float* C = (float*)Cv + (long)zb * sC;
    const float* rs = rowsum + (long)zb * S_;
#pragma unroll
    for (int i = 0; i < 4; ++i) {
#pragma unroll
      for (int r = 0; r < 4; ++r) {
        const int row = row0 + wm + i * 16 + quad * 4 + r;
        const float inv = 1.0f / rs[row];
#pragma unroll
        for (int j = 0; j < 4; ++j) {
          const int col = col0 + wn + j * 16 + lrow;
          if (KSPLIT == 1)
            C[(long)row * ldc + col] = acc[i][j][r] * inv;
          else
            atomicAdd(&C[(long)row * ldc + col], acc[i][j][r] * inv);
        }
      }
    }
  } else if (MODE == 7) {
    // scores: P~ = exp(s*scale) (no max subtraction: |s| <~ 6), bf16 store,
    // fp32 row-sums via shuffle-reduce over lrow + one atomicAdd per row/wave.
    unsigned short* C = (unsigned short*)Cv + (long)zb * sC;
    float* rs = rowsum + (long)zb * S_;
    float rsump[4][4];
#pragma unroll
    for (int i = 0; i < 4; ++i)
#pragma unroll
      for (int r = 0; r < 4; ++r) rsump[i][r] = 0.f;
#pragma unroll
    for (int j = 0; j < 4; ++j) {
      const int col = col0 + wn + j * 16 + lrow;
#pragma unroll
      for (int i = 0; i < 4; ++i) {
#pragma unroll
        for (int r = 0; r < 4; ++r) {
          const int row = row0 + wm + i * 16 + quad * 4 + r;
          const float e = __expf(acc[i][j][r] * scale);
          rsump[i][r] += e;
          C[(long)row * ldc + col] = f2bf(e);
        }
      }
    }
#pragma unroll
    for (int i = 0; i < 4; ++i) {
#pragma unroll
      for (int r = 0; r < 4; ++r) {
        float v = rsump[i][r];
        v += __shfl_xor(v, 1);
        v += __shfl_xor(v, 2);
        v += __shfl_xor(v, 4);
        v += __shfl_xor(v, 8);
        if (lrow == 0)
          atomicAdd(&rs[row0 + wm + i * 16 + quad * 4 + r], v);
      }
    }
  } else {  // MODE 6: fused QKV
    if (col0 < 2048) {
      unsigned short* C = (unsigned short*)Cv;
#pragma unroll
      for (int j = 0; j < 4; ++j) {
        const int col = col0 + wn + j * 16 + lrow;
        const float bcol = (col < E_) ? bias[col] : bias_b[col - E_];
#pragma unroll
        for (int i = 0; i < 4; ++i) {
#pragma unroll
          for (int r = 0; r < 4; ++r) {
            const int row = row0 + wm + i * 16 + quad * 4 + r;
            C[(long)row * ldc + col] = f2bf(acc[i][j][r] + bcol);
          }
        }
      }
    } else {
      // V block: write transposed. e = col-2048; Vt[e][bs], bs-run of 4 contiguous.
#pragma unroll
      for (int j = 0; j < 4; ++j) {
        const int e = col0 + wn + j * 16 + lrow - 2048;
        const float bv_ = bias_v[e];
#pragma unroll
        for (int i = 0; i < 4; ++i) {
          const int row = row0 + wm + i * 16 + quad * 4;  // base of 4 consecutive bs
          ushort4v o;
          o.x = f2bf(acc[i][j][0] + bv_);
          o.y = f2bf(acc[i][j][1] + bv_);
          o.z = f2bf(acc[i][j][2] + bv_);
          o.w = f2bf(acc[i][j][3] + bv_);
          *(ushort4v*)(VtOut + (long)e * (B_ * S_) + row) = o;
        }
      }
    }
  }
}

// ---------------------------------------------------------------------------
extern "C" void kernel_launch(void* const* d_in, const int* in_sizes, int n_in,
                              void* d_out, int out_size, void* d_ws, size_t ws_size,
                              hipStream_t stream) {
  const float* x    = (const float*)d_in[0];
  const float* wq_w = (const float*)d_in[1];
  const float* wq_b = (const float*)d_in[2];
  const float* wk_w = (const float*)d_in[3];
  const float* wk_b = (const float*)d_in[4];
  const float* wv_w = (const float*)d_in[5];
  const float* wv_b = (const float*)d_in[6];
  float* out = (float*)d_out;

  const long NX = (long)B_ * S_ * E_;  // 8388608
  const long NW = (long)E_ * E_;       // 1048576
  char* ws = (char*)d_ws;
  bf16* xb  = (bf16*)ws; ws += NX * 2;
  bf16* wqb = (bf16*)ws; ws += NW * 2;   // xb,wqb,wkb,wvb contiguous (cvt_all writes all four)
  bf16* wkb = (bf16*)ws; ws += NW * 2;
  bf16* wvb = (bf16*)ws; ws += NW * 2;
  bf16* QK  = (bf16*)ws; ws += 2 * NX * 2;   // [8192 x 2048]: cols 0..1023 = Q, 1024..2047 = K
  bf16* Vt  = (bf16*)ws; ws += NX * 2;       // [1024 x 8192] (V transposed)
  bf16* Sc  = (bf16*)ws; ws += (long)B_ * S_ * S_ * 2;   // exp-scores
  float* rowsum = (float*)ws; ws += (long)B_ * S_ * 4;   // fp32 row sums

  // single merged convert dispatch (x + 3 weights + rowsum zeroing)
  cvt_all<<<dim3(11272), 256, 0, stream>>>(
      x, wq_w, wk_w, wv_w, (unsigned short*)xb, rowsum);
  // zero out for PV split-K atomic accumulation (ws/out poisoned pre-launch)
  hipMemsetAsync(out, 0, (size_t)NX * 4, stream);

  dim3 blk(256);
  // QKV = x @ [Wq;Wk;Wv]^T + bias  [8192 x 3072], linear grid.
  gemm_bt<6, 0, 24, 1><<<dim3((3 * E_) / 128, (B_ * S_) / 128, 1), blk, 0, stream>>>(
      xb, wqb, QK, wq_b, wk_b, wv_b, (unsigned short*)Vt, nullptr,
      B_ * S_, 3 * E_, E_, E_, E_, 2 * E_, 0, 0, 0, 1.f, 64);
  // exp-scores = exp(Q @ K^T / 32) + atomic row sums. SWZ=1 batch pinning.
  gemm_bt<7, 1, 16, 1><<<dim3(1024, 1, 1), blk, 0, stream>>>(
      QK, QK + E_, Sc, nullptr, nullptr, nullptr, nullptr, rowsum,
      S_, S_, E_, 2 * E_, 2 * E_, S_,
      (long)S_ * 2 * E_, (long)S_ * 2 * E_, (long)S_ * S_, 0.03125f, 16);
  // out = (P~ @ V) / rowsum, per batch. Split-K=2: 1024 blocks (4/CU vs 2/CU),
  // each block K=1024, atomicAdd into pre-zeroed out.
  gemm_bt<8, 1, 8, 2><<<dim3(1024, 1, 1), blk, 0, stream>>>(
      Sc, Vt, out, nullptr, nullptr, nullptr, nullptr, rowsum,
      S_, E_, S_, S_, B_ * S_, E_,
      (long)S_ * S_, (long)S_, (long)S_ * E_, 1.f, 16);
}

// Round 7
// 271.643 us; speedup vs baseline: 1.0778x; 1.0778x over previous
//
#include <hip/hip_runtime.h>
#include <hip/hip_bf16.h>
#include <stdint.h>

#define B_ 4
#define S_ 2048
#define E_ 1024

// Session ledger:
//  R1/R2: 8-phase 256^2 port — correct but ~80us/25% MfmaUtil (worse than
//    2-barrier 75us/28%). Theory: hipcc inserts conservative vmcnt drains
//    around global_load_lds + ds_read phases. PARKED (2 strikes, no disasm).
//  R3: revert + memset-fusion = baseline 256.5us. ANCHOR.
//  R4: PV BN=64 + compact Q/K = 262.1 (BN=64 doubled Sc re-reads). Reverted.
//  R5: PV split-K=2 = 292.8 (16M fp32 atomicAdds, 64MB RMW). Occupancy
//    theory for PV falsified twice; PV ~60us is its structure-local optimum.
//  R6: fused x-convert into QKV A-staging: NaN. BUG: wrote row-group g at
//    ldsAw + g*1024 elements; correct image is g*2048 elements (32 rows x
//    64 el/row). Rows 112-127 stayed poisoned, collisions corrupted rest.
//  R7 (this): the one-line fix (g*2048). Everything else identical to R6.
//    Derived timings @R3: cvt 13, QKV 77 (673 TF), scores ~100 (687 TF),
//    PV ~60 (573 TF), gaps ~6. All GEMMs at the 2-barrier structure rate.

typedef __bf16 bf16;
typedef __attribute__((ext_vector_type(8))) __bf16 bf16x8;
typedef __attribute__((ext_vector_type(4))) float f32x4;
typedef __attribute__((ext_vector_type(4))) float float4v;
typedef __attribute__((ext_vector_type(4))) unsigned int uint4v;
typedef __attribute__((ext_vector_type(4))) unsigned short ushort4v;

__device__ inline unsigned short f2bf(float f) {
  union { float f; unsigned int u; } c; c.f = f;
  unsigned int u = c.u;
  unsigned int r = (u + 0x7FFFu + ((u >> 16) & 1u)) >> 16;
  return (unsigned short)r;
}

__device__ inline void load16_to_lds(const void* g, void* l) {
  __builtin_amdgcn_global_load_lds(
      (const __attribute__((address_space(1))) void*)g,
      (__attribute__((address_space(3))) void*)l,
      16, 0, 0);
}

// ---------------------------------------------------------------------------
// Weight fp32->bf16 converter (3 weights, 1024 blocks each) + rowsum zeroing
// (8 blocks). x is no longer pre-converted: QKV stages it from fp32 directly.
// ---------------------------------------------------------------------------
__global__ __launch_bounds__(256) void cvt_all(
    const float* __restrict__ w0, const float* __restrict__ w1,
    const float* __restrict__ w2, unsigned short* __restrict__ out,
    float* __restrict__ rowsum) {
  if (blockIdx.x >= 3072) {  // 8 blocks: zero rowsum[8192] (fp32)
    rowsum[(blockIdx.x - 3072) * 256 + threadIdx.x] = 0.f;
    return;
  }
  const long off = (long)blockIdx.x * 256 + threadIdx.x;  // float4 units
  const float* in;
  long ibase;
  if (blockIdx.x < 1024)       { in = w0; ibase = 0; }
  else if (blockIdx.x < 2048)  { in = w1; ibase = 1024L * 256; }
  else                         { in = w2; ibase = 2048L * 256; }
  float4v f = ((const float4v*)in)[off - ibase];
  ushort4v o;
  o.x = f2bf(f.x); o.y = f2bf(f.y); o.z = f2bf(f.z); o.w = f2bf(f.w);
  ((ushort4v*)out)[off] = o;
}

// ---------------------------------------------------------------------------
// bt-GEMM: C[m][n] = sum_k A[m][k] * B[n][k]   [proven K-loop]
// SWZ 0: (x,y,z) = blockIdx      SWZ 1: 1D grid, XCD-pinned batches.
// AF32 1: A operand is fp32 (x), reg-staged with in-register RTNE convert +
//   ds_write_b128 producing the byte-identical LDS image the global_load_lds
//   scatter produced: row-group g (rows r0+32g) at element wave*512 + lane*8
//   + g*2048 (32 rows x 64 el = 2048 el per group). K-loop untouched.
// MODE 6: fused QKV projection epilogue (QK rows + transposed V)
// MODE 7: scores: write exp(acc*scale) bf16 + atomic fp32 row-sums
// MODE 8: PV: fp32 out, divided by rowsum[row]
// ---------------------------------------------------------------------------
template <int MODE, int SWZ, int NXT, int AF32>
__global__ __launch_bounds__(256, 4) void gemm_bt(
    const bf16* __restrict__ A, const float* __restrict__ Af,
    const bf16* __restrict__ B, void* __restrict__ Cv,
    const float* __restrict__ bias, const float* __restrict__ bias_b,
    const float* __restrict__ bias_v, unsigned short* __restrict__ VtOut,
    float* __restrict__ rowsum,
    int M, int N, int K, int lda, int ldb, int ldc,
    long sA, long sB, long sC, float scale, int nyt) {
  __shared__ bf16 As[128 * 64];
  __shared__ bf16 Bs[128 * 64];

  int xt, yt, zb;
  if (SWZ == 0) {
    xt = blockIdx.x; yt = blockIdx.y; zb = blockIdx.z;
  } else {  // SWZ == 1
    const int flat = blockIdx.x;
    const int xcd = flat & 7;
    const int local = flat >> 3;            // 0 .. NXT*nyt/2 - 1
    zb = xcd >> 1;
    const int w = (xcd & 1) * (NXT * nyt / 2) + local;
    xt = w % NXT; yt = w / NXT;
  }

  A += (long)zb * sA;
  B += (long)zb * sB;
  const int tid = threadIdx.x;
  const int wave = tid >> 6;
  const int lane = tid & 63;
  const int lrow = lane & 15;
  const int quad = lane >> 4;
  const int row0 = yt * 128;
  const int col0 = xt * 128;
  const int wm = (wave >> 1) * 64;
  const int wn = (wave & 1) * 64;

  f32x4 acc[4][4] = {};

  // staging geometry: r0 in [0,32), c0 in {0,8,...,56}; rows r0+32i
  const int r0 = wave * 8 + (lane >> 3);
  const int c0 = (lane & 7) * 8;

  const bf16* pA0 = A + (long)(row0 + r0) * lda + c0;
  const bf16* pA1 = pA0 + 32L * lda;
  const bf16* pA2 = pA0 + 64L * lda;
  const bf16* pA3 = pA0 + 96L * lda;
  const float* pAf = AF32 ? (Af + (long)(row0 + r0) * lda + c0) : nullptr;
  const bf16* pB0 = B + (long)(col0 + r0) * ldb + c0;
  const bf16* pB1 = pB0 + 32L * ldb;
  const bf16* pB2 = pB0 + 64L * ldb;
  const bf16* pB3 = pB0 + 96L * ldb;
  bf16* ldsA = As + wave * 512;  // wave-uniform; HW scatters lane*16B
  bf16* ldsB = Bs + wave * 512;
  bf16* const ldsAw = As + wave * 512 + lane * 8;  // this thread's 16B slot

  for (int ks = 0; ks < K; ks += 64) {
    if constexpr (AF32) {
      // reg-stage A from fp32: 2 float4 per row-group, RTNE cvt, ds_write.
      float4v fa[4][2];
#pragma unroll
      for (int g = 0; g < 4; ++g) {
        const float* p = pAf + (long)(32 * g) * lda;
        fa[g][0] = *(const float4v*)(p);
        fa[g][1] = *(const float4v*)(p + 4);
      }
      load16_to_lds(pB0, ldsB);
      load16_to_lds(pB1, ldsB + 2048);
      load16_to_lds(pB2, ldsB + 4096);
      load16_to_lds(pB3, ldsB + 6144);
#pragma unroll
      for (int g = 0; g < 4; ++g) {
        bf16x8 w;
        w[0] = (bf16)fa[g][0].x; w[1] = (bf16)fa[g][0].y;
        w[2] = (bf16)fa[g][0].z; w[3] = (bf16)fa[g][0].w;
        w[4] = (bf16)fa[g][1].x; w[5] = (bf16)fa[g][1].y;
        w[6] = (bf16)fa[g][1].z; w[7] = (bf16)fa[g][1].w;
        *(bf16x8*)(ldsAw + g * 2048) = w;  // 32 rows x 64 el = 2048 el/group
      }
      pAf += 64;
    } else {
      load16_to_lds(pA0, ldsA);
      load16_to_lds(pA1, ldsA + 2048);
      load16_to_lds(pA2, ldsA + 4096);
      load16_to_lds(pA3, ldsA + 6144);
      load16_to_lds(pB0, ldsB);
      load16_to_lds(pB1, ldsB + 2048);
      load16_to_lds(pB2, ldsB + 4096);
      load16_to_lds(pB3, ldsB + 6144);
      pA0 += 64; pA1 += 64; pA2 += 64; pA3 += 64;
    }
    __syncthreads();
#pragma unroll
    for (int kk = 0; kk < 64; kk += 32) {
      bf16x8 af[4], bfr[4];
#pragma unroll
      for (int i = 0; i < 4; ++i)
        af[i] = *(const bf16x8*)(As + (wm + i * 16 + lrow) * 64 + kk + quad * 8);
#pragma unroll
      for (int j = 0; j < 4; ++j)
        bfr[j] = *(const bf16x8*)(Bs + (wn + j * 16 + lrow) * 64 + kk + quad * 8);
#pragma unroll
      for (int i = 0; i < 4; ++i)
#pragma unroll
        for (int j = 0; j < 4; ++j)
          acc[i][j] = __builtin_amdgcn_mfma_f32_16x16x32_bf16(af[i], bfr[j], acc[i][j], 0, 0, 0);
    }
    __syncthreads();
    pB0 += 64; pB1 += 64; pB2 += 64; pB3 += 64;
  }

  // epilogue: D mapping (verified m89/m91): row = quad*4 + r (m), col = lrow (n)
  if (MODE == 8) {
    // PV: fp32 out, scaled by 1/rowsum[row] (rowsum L2-hot, 32 KB)
    float* C = (float*)Cv + (long)zb * sC;
    const float* rs = rowsum + (long)zb * S_;
#pragma unroll
    for (int i = 0; i < 4; ++i) {
#pragma unroll
      for (int r = 0; r < 4; ++r) {
        const int row = row0 + wm + i * 16 + quad * 4 + r;
        const float inv = 1.0f / rs[row];
#pragma unroll
        for (int j = 0; j < 4; ++j) {
          const int col = col0 + wn + j * 16 + lrow;
          C[(long)row * ldc + col] = acc[i][j][r] * inv;
        }
      }
    }
  } else if (MODE == 7) {
    // scores: P~ = exp(s*scale) (no max subtraction: |s| <~ 6), bf16 store,
    // fp32 row-sums via shuffle-reduce over lrow + one atomicAdd per row/wave.
    unsigned short* C = (unsigned short*)Cv + (long)zb * sC;
    float* rs = rowsum + (long)zb * S_;
    float rsump[4][4];
#pragma unroll
    for (int i = 0; i < 4; ++i)
#pragma unroll
      for (int r = 0; r < 4; ++r) rsump[i][r] = 0.f;
#pragma unroll
    for (int j = 0; j < 4; ++j) {
      const int col = col0 + wn + j * 16 + lrow;
#pragma unroll
      for (int i = 0; i < 4; ++i) {
#pragma unroll
        for (int r = 0; r < 4; ++r) {
          const int row = row0 + wm + i * 16 + quad * 4 + r;
          const float e = __expf(acc[i][j][r] * scale);
          rsump[i][r] += e;
          C[(long)row * ldc + col] = f2bf(e);
        }
      }
    }
#pragma unroll
    for (int i = 0; i < 4; ++i) {
#pragma unroll
      for (int r = 0; r < 4; ++r) {
        float v = rsump[i][r];
        v += __shfl_xor(v, 1);
        v += __shfl_xor(v, 2);
        v += __shfl_xor(v, 4);
        v += __shfl_xor(v, 8);
        if (lrow == 0)
          atomicAdd(&rs[row0 + wm + i * 16 + quad * 4 + r], v);
      }
    }
  } else {  // MODE 6: fused QKV
    if (col0 < 2048) {
      unsigned short* C = (unsigned short*)Cv;
#pragma unroll
      for (int j = 0; j < 4; ++j) {
        const int col = col0 + wn + j * 16 + lrow;
        const float bcol = (col < E_) ? bias[col] : bias_b[col - E_];
#pragma unroll
        for (int i = 0; i < 4; ++i) {
#pragma unroll
          for (int r = 0; r < 4; ++r) {
            const int row = row0 + wm + i * 16 + quad * 4 + r;
            C[(long)row * ldc + col] = f2bf(acc[i][j][r] + bcol);
          }
        }
      }
    } else {
      // V block: write transposed. e = col-2048; Vt[e][bs], bs-run of 4 contiguous.
#pragma unroll
      for (int j = 0; j < 4; ++j) {
        const int e = col0 + wn + j * 16 + lrow - 2048;
        const float bv_ = bias_v[e];
#pragma unroll
        for (int i = 0; i < 4; ++i) {
          const int row = row0 + wm + i * 16 + quad * 4;  // base of 4 consecutive bs
          ushort4v o;
          o.x = f2bf(acc[i][j][0] + bv_);
          o.y = f2bf(acc[i][j][1] + bv_);
          o.z = f2bf(acc[i][j][2] + bv_);
          o.w = f2bf(acc[i][j][3] + bv_);
          *(ushort4v*)(VtOut + (long)e * (B_ * S_) + row) = o;
        }
      }
    }
  }
}

// ---------------------------------------------------------------------------
extern "C" void kernel_launch(void* const* d_in, const int* in_sizes, int n_in,
                              void* d_out, int out_size, void* d_ws, size_t ws_size,
                              hipStream_t stream) {
  const float* x    = (const float*)d_in[0];
  const float* wq_w = (const float*)d_in[1];
  const float* wq_b = (const float*)d_in[2];
  const float* wk_w = (const float*)d_in[3];
  const float* wk_b = (const float*)d_in[4];
  const float* wv_w = (const float*)d_in[5];
  const float* wv_b = (const float*)d_in[6];
  float* out = (float*)d_out;

  const long NX = (long)B_ * S_ * E_;  // 8388608
  const long NW = (long)E_ * E_;       // 1048576
  char* ws = (char*)d_ws;
  bf16* wqb = (bf16*)ws; ws += NW * 2;   // wqb,wkb,wvb contiguous (cvt_all)
  bf16* wkb = (bf16*)ws; ws += NW * 2;
  bf16* wvb = (bf16*)ws; ws += NW * 2;
  bf16* QK  = (bf16*)ws; ws += 2 * NX * 2;   // [8192 x 2048]: cols 0..1023 = Q, 1024..2047 = K
  bf16* Vt  = (bf16*)ws; ws += NX * 2;       // [1024 x 8192] (V transposed)
  bf16* Sc  = (bf16*)ws; ws += (long)B_ * S_ * S_ * 2;   // exp-scores
  float* rowsum = (float*)ws; ws += (long)B_ * S_ * 4;   // fp32 row sums

  // weights convert + rowsum zeroing (x handled in-kernel by QKV)
  cvt_all<<<dim3(3080), 256, 0, stream>>>(
      wq_w, wk_w, wv_w, (unsigned short*)wqb, rowsum);

  dim3 blk(256);
  // QKV = x @ [Wq;Wk;Wv]^T + bias  [8192 x 3072]; A = x fp32 reg-staged.
  gemm_bt<6, 0, 24, 1><<<dim3((3 * E_) / 128, (B_ * S_) / 128, 1), blk, 0, stream>>>(
      nullptr, x, wqb, QK, wq_b, wk_b, wv_b, (unsigned short*)Vt, nullptr,
      B_ * S_, 3 * E_, E_, E_, E_, 2 * E_, 0, 0, 0, 1.f, 64);
  // exp-scores = exp(Q @ K^T / 32) + atomic row sums. SWZ=1 batch pinning.
  gemm_bt<7, 1, 16, 0><<<dim3(1024, 1, 1), blk, 0, stream>>>(
      QK, nullptr, QK + E_, Sc, nullptr, nullptr, nullptr, nullptr, rowsum,
      S_, S_, E_, 2 * E_, 2 * E_, S_,
      (long)S_ * 2 * E_, (long)S_ * 2 * E_, (long)S_ * S_, 0.03125f, 16);
  // out = (P~ @ V) / rowsum, per batch, fp32 out. SWZ=1 batch pinning.
  gemm_bt<8, 1, 8, 0><<<dim3(512, 1, 1), blk, 0, stream>>>(
      Sc, nullptr, Vt, out, nullptr, nullptr, nullptr, nullptr, rowsum,
      S_, E_, S_, S_, B_ * S_, E_,
      (long)S_ * S_, (long)S_, (long)S_ * E_, 1.f, 16);
}

// Round 8
// 256.730 us; speedup vs baseline: 1.1404x; 1.0581x over previous
//
#include <hip/hip_runtime.h>
#include <hip/hip_bf16.h>
#include <stdint.h>

#define B_ 4
#define S_ 2048
#define E_ 1024

// Session ledger:
//  R1/R2: 8-phase 256^2 port — correct but slower (~80us/25% MfmaUtil vs
//    75/28%). Theory: compiler-inserted conservative vmcnt drains. PARKED.
//  R3: ANCHOR = 256.5us. cvt 13, QKV 77 (669 TF), scores ~100 (344 TF),
//    PV ~60 (573 TF), gaps ~6.
//  R4: PV BN=64 + compact Q/K bundled = 262.1. Not decomposable. Reverted.
//  R5: PV split-K=2 = 292.8 (64MB fp32 atomicAdd RMW). PV occupancy theory
//    falsified twice; PV ~60us is its structure-local optimum.
//  R6/R7: x-convert fused into QKV A-staging: R6 NaN (LDS offset bug),
//    R7 correct but QKV 95-97us / FETCH 145MB (fp32 x re-read per col-tile
//    defeats L2). Fusion REJECTED; pre-convert (R3) is the right trade.
//  R8 (this): isolate R4's OTHER half — compact Q/K (2KB row stride) for
//    scores' operands, everything else R3-exact. Theory: scores' 344 TF
//    (vs QKV 669) is 4KB power-of-2 row-stride channel/L2-set aliasing.
//    Null => revert to R3 and declare plateau.

typedef __bf16 bf16;
typedef __attribute__((ext_vector_type(8))) __bf16 bf16x8;
typedef __attribute__((ext_vector_type(4))) float f32x4;
typedef __attribute__((ext_vector_type(4))) float float4v;
typedef __attribute__((ext_vector_type(4))) unsigned int uint4v;
typedef __attribute__((ext_vector_type(4))) unsigned short ushort4v;

__device__ inline unsigned short f2bf(float f) {
  union { float f; unsigned int u; } c; c.f = f;
  unsigned int u = c.u;
  unsigned int r = (u + 0x7FFFu + ((u >> 16) & 1u)) >> 16;
  return (unsigned short)r;
}

__device__ inline void load16_to_lds(const void* g, void* l) {
  __builtin_amdgcn_global_load_lds(
      (const __attribute__((address_space(1))) void*)g,
      (__attribute__((address_space(3))) void*)l,
      16, 0, 0);
}

// ---------------------------------------------------------------------------
// Merged fp32->bf16 converter: x (8192 blocks) + 3 weights (1024 each) +
// rowsum zeroing (8 blocks).
// ---------------------------------------------------------------------------
__global__ __launch_bounds__(256) void cvt_all(
    const float* __restrict__ x, const float* __restrict__ w0,
    const float* __restrict__ w1, const float* __restrict__ w2,
    unsigned short* __restrict__ out, float* __restrict__ rowsum) {
  if (blockIdx.x >= 11264) {  // 8 blocks: zero rowsum[8192] (fp32)
    rowsum[(blockIdx.x - 11264) * 256 + threadIdx.x] = 0.f;
    return;
  }
  const long off = (long)blockIdx.x * 256 + threadIdx.x;  // float4 units
  const float* in;
  long ibase;
  if (blockIdx.x < 8192)       { in = x;  ibase = 0; }
  else if (blockIdx.x < 9216)  { in = w0; ibase = 8192L * 256; }
  else if (blockIdx.x < 10240) { in = w1; ibase = 9216L * 256; }
  else                         { in = w2; ibase = 10240L * 256; }
  float4v f = ((const float4v*)in)[off - ibase];
  ushort4v o;
  o.x = f2bf(f.x); o.y = f2bf(f.y); o.z = f2bf(f.z); o.w = f2bf(f.w);
  ((ushort4v*)out)[off] = o;
}

// ---------------------------------------------------------------------------
// bt-GEMM: C[m][n] = sum_k A[m][k] * B[n][k]   [proven K-loop, unchanged]
// SWZ 0: (x,y,z) = blockIdx      SWZ 1: 1D grid, XCD-pinned batches.
// MODE 6: fused QKV epilogue -> compact Q [8192x1024], K [8192x1024] (=Q+NX),
//         V transposed [1024x8192]. ldc = 1024 for Q/K stores.
// MODE 7: scores: write exp(acc*scale) bf16 + atomic fp32 row-sums
// MODE 8: PV: fp32 out, divided by rowsum[row]
// ---------------------------------------------------------------------------
template <int MODE, int SWZ, int NXT>
__global__ __launch_bounds__(256, 4) void gemm_bt(
    const bf16* __restrict__ A, const bf16* __restrict__ B, void* __restrict__ Cv,
    const float* __restrict__ bias, const float* __restrict__ bias_b,
    const float* __restrict__ bias_v, unsigned short* __restrict__ VtOut,
    float* __restrict__ rowsum,
    int M, int N, int K, int lda, int ldb, int ldc,
    long sA, long sB, long sC, float scale, int nyt) {
  __shared__ bf16 As[128 * 64];
  __shared__ bf16 Bs[128 * 64];

  int xt, yt, zb;
  if (SWZ == 0) {
    xt = blockIdx.x; yt = blockIdx.y; zb = blockIdx.z;
  } else {  // SWZ == 1
    const int flat = blockIdx.x;
    const int xcd = flat & 7;
    const int local = flat >> 3;            // 0 .. NXT*nyt/2 - 1
    zb = xcd >> 1;
    const int w = (xcd & 1) * (NXT * nyt / 2) + local;
    xt = w % NXT; yt = w / NXT;
  }

  A += (long)zb * sA;
  B += (long)zb * sB;
  const int tid = threadIdx.x;
  const int wave = tid >> 6;
  const int lane = tid & 63;
  const int lrow = lane & 15;
  const int quad = lane >> 4;
  const int row0 = yt * 128;
  const int col0 = xt * 128;
  const int wm = (wave >> 1) * 64;
  const int wn = (wave & 1) * 64;

  f32x4 acc[4][4] = {};

  // staging geometry: r0 in [0,32), c0 in {0,8,...,56}; rows r0+32i
  const int r0 = wave * 8 + (lane >> 3);
  const int c0 = (lane & 7) * 8;

  const bf16* pA0 = A + (long)(row0 + r0) * lda + c0;
  const bf16* pA1 = pA0 + 32L * lda;
  const bf16* pA2 = pA0 + 64L * lda;
  const bf16* pA3 = pA0 + 96L * lda;
  const bf16* pB0 = B + (long)(col0 + r0) * ldb + c0;
  const bf16* pB1 = pB0 + 32L * ldb;
  const bf16* pB2 = pB0 + 64L * ldb;
  const bf16* pB3 = pB0 + 96L * ldb;
  bf16* ldsA = As + wave * 512;  // wave-uniform; HW scatters lane*16B
  bf16* ldsB = Bs + wave * 512;

  for (int ks = 0; ks < K; ks += 64) {
    load16_to_lds(pA0, ldsA);
    load16_to_lds(pA1, ldsA + 2048);
    load16_to_lds(pA2, ldsA + 4096);
    load16_to_lds(pA3, ldsA + 6144);
    load16_to_lds(pB0, ldsB);
    load16_to_lds(pB1, ldsB + 2048);
    load16_to_lds(pB2, ldsB + 4096);
    load16_to_lds(pB3, ldsB + 6144);
    __syncthreads();
#pragma unroll
    for (int kk = 0; kk < 64; kk += 32) {
      bf16x8 af[4], bfr[4];
#pragma unroll
      for (int i = 0; i < 4; ++i)
        af[i] = *(const bf16x8*)(As + (wm + i * 16 + lrow) * 64 + kk + quad * 8);
#pragma unroll
      for (int j = 0; j < 4; ++j)
        bfr[j] = *(const bf16x8*)(Bs + (wn + j * 16 + lrow) * 64 + kk + quad * 8);
#pragma unroll
      for (int i = 0; i < 4; ++i)
#pragma unroll
        for (int j = 0; j < 4; ++j)
          acc[i][j] = __builtin_amdgcn_mfma_f32_16x16x32_bf16(af[i], bfr[j], acc[i][j], 0, 0, 0);
    }
    __syncthreads();
    pA0 += 64; pA1 += 64; pA2 += 64; pA3 += 64;
    pB0 += 64; pB1 += 64; pB2 += 64; pB3 += 64;
  }

  // epilogue: D mapping (verified m89/m91): row = quad*4 + r (m), col = lrow (n)
  if (MODE == 8) {
    // PV: fp32 out, scaled by 1/rowsum[row] (rowsum L2-hot, 32 KB)
    float* C = (float*)Cv + (long)zb * sC;
    const float* rs = rowsum + (long)zb * S_;
#pragma unroll
    for (int i = 0; i < 4; ++i) {
#pragma unroll
      for (int r = 0; r < 4; ++r) {
        const int row = row0 + wm + i * 16 + quad * 4 + r;
        const float inv = 1.0f / rs[row];
#pragma unroll
        for (int j = 0; j < 4; ++j) {
          const int col = col0 + wn + j * 16 + lrow;
          C[(long)row * ldc + col] = acc[i][j][r] * inv;
        }
      }
    }
  } else if (MODE == 7) {
    // scores: P~ = exp(s*scale) (no max subtraction: |s| <~ 6), bf16 store,
    // fp32 row-sums via shuffle-reduce over lrow + one atomicAdd per row/wave.
    unsigned short* C = (unsigned short*)Cv + (long)zb * sC;
    float* rs = rowsum + (long)zb * S_;
    float rsump[4][4];
#pragma unroll
    for (int i = 0; i < 4; ++i)
#pragma unroll
      for (int r = 0; r < 4; ++r) rsump[i][r] = 0.f;
#pragma unroll
    for (int j = 0; j < 4; ++j) {
      const int col = col0 + wn + j * 16 + lrow;
#pragma unroll
      for (int i = 0; i < 4; ++i) {
#pragma unroll
        for (int r = 0; r < 4; ++r) {
          const int row = row0 + wm + i * 16 + quad * 4 + r;
          const float e = __expf(acc[i][j][r] * scale);
          rsump[i][r] += e;
          C[(long)row * ldc + col] = f2bf(e);
        }
      }
    }
#pragma unroll
    for (int i = 0; i < 4; ++i) {
#pragma unroll
      for (int r = 0; r < 4; ++r) {
        float v = rsump[i][r];
        v += __shfl_xor(v, 1);
        v += __shfl_xor(v, 2);
        v += __shfl_xor(v, 4);
        v += __shfl_xor(v, 8);
        if (lrow == 0)
          atomicAdd(&rs[row0 + wm + i * 16 + quad * 4 + r], v);
      }
    }
  } else {  // MODE 6: fused QKV. Q, K as separate compact [8192 x 1024] bufs.
    if (col0 < 2 * E_) {
      unsigned short* Cq = (unsigned short*)Cv;              // Q buffer
      unsigned short* Ck = Cq + (long)B_ * S_ * E_;          // K buffer
      unsigned short* C;
      const float* bb;
      int cbase;
      if (col0 < E_) { C = Cq; bb = bias;   cbase = col0; }
      else           { C = Ck; bb = bias_b; cbase = col0 - E_; }
#pragma unroll
      for (int j = 0; j < 4; ++j) {
        const int col = cbase + wn + j * 16 + lrow;
        const float bcol = bb[col];
#pragma unroll
        for (int i = 0; i < 4; ++i) {
#pragma unroll
          for (int r = 0; r < 4; ++r) {
            const int row = row0 + wm + i * 16 + quad * 4 + r;
            C[(long)row * ldc + col] = f2bf(acc[i][j][r] + bcol);
          }
        }
      }
    } else {
      // V block: write transposed. e = col-2048; Vt[e][bs], bs-run of 4 contiguous.
#pragma unroll
      for (int j = 0; j < 4; ++j) {
        const int e = col0 + wn + j * 16 + lrow - 2 * E_;
        const float bv_ = bias_v[e];
#pragma unroll
        for (int i = 0; i < 4; ++i) {
          const int row = row0 + wm + i * 16 + quad * 4;  // base of 4 consecutive bs
          ushort4v o;
          o.x = f2bf(acc[i][j][0] + bv_);
          o.y = f2bf(acc[i][j][1] + bv_);
          o.z = f2bf(acc[i][j][2] + bv_);
          o.w = f2bf(acc[i][j][3] + bv_);
          *(ushort4v*)(VtOut + (long)e * (B_ * S_) + row) = o;
        }
      }
    }
  }
}

// ---------------------------------------------------------------------------
extern "C" void kernel_launch(void* const* d_in, const int* in_sizes, int n_in,
                              void* d_out, int out_size, void* d_ws, size_t ws_size,
                              hipStream_t stream) {
  const float* x    = (const float*)d_in[0];
  const float* wq_w = (const float*)d_in[1];
  const float* wq_b = (const float*)d_in[2];
  const float* wk_w = (const float*)d_in[3];
  const float* wk_b = (const float*)d_in[4];
  const float* wv_w = (const float*)d_in[5];
  const float* wv_b = (const float*)d_in[6];
  float* out = (float*)d_out;

  const long NX = (long)B_ * S_ * E_;  // 8388608
  const long NW = (long)E_ * E_;       // 1048576
  char* ws = (char*)d_ws;
  bf16* xb  = (bf16*)ws; ws += NX * 2;
  bf16* wqb = (bf16*)ws; ws += NW * 2;   // xb,wqb,wkb,wvb contiguous (cvt_all)
  bf16* wkb = (bf16*)ws; ws += NW * 2;
  bf16* wvb = (bf16*)ws; ws += NW * 2;
  bf16* Qc  = (bf16*)ws; ws += NX * 2;       // [8192 x 1024] Q compact
  bf16* Kc  = (bf16*)ws; ws += NX * 2;       // [8192 x 1024] K compact (= Qc + NX)
  bf16* Vt  = (bf16*)ws; ws += NX * 2;       // [1024 x 8192] (V transposed)
  bf16* Sc  = (bf16*)ws; ws += (long)B_ * S_ * S_ * 2;   // exp-scores
  float* rowsum = (float*)ws; ws += (long)B_ * S_ * 4;   // fp32 row sums

  // single merged convert dispatch (x + 3 weights + rowsum zeroing)
  cvt_all<<<dim3(11272), 256, 0, stream>>>(
      x, wq_w, wk_w, wv_w, (unsigned short*)xb, rowsum);

  dim3 blk(256);
  // QKV = x @ [Wq;Wk;Wv]^T + bias  [8192 x 3072]; Q,K compact (ldc=1024) + Vt.
  gemm_bt<6, 0, 24><<<dim3((3 * E_) / 128, (B_ * S_) / 128, 1), blk, 0, stream>>>(
      xb, wqb, Qc, wq_b, wk_b, wv_b, (unsigned short*)Vt, nullptr,
      B_ * S_, 3 * E_, E_, E_, E_, E_, 0, 0, 0, 1.f, 64);
  // exp-scores = exp(Q @ K^T / 32) + atomic row sums. SWZ=1 batch pinning.
  // Operands now 2KB row stride (compact) instead of 4KB interleaved.
  gemm_bt<7, 1, 16><<<dim3(1024, 1, 1), blk, 0, stream>>>(
      Qc, Kc, Sc, nullptr, nullptr, nullptr, nullptr, rowsum,
      S_, S_, E_, E_, E_, S_,
      (long)S_ * E_, (long)S_ * E_, (long)S_ * S_, 0.03125f, 16);
  // out = (P~ @ V) / rowsum, per batch, fp32 out. SWZ=1 batch pinning.
  gemm_bt<8, 1, 8><<<dim3(512, 1, 1), blk, 0, stream>>>(
      Sc, Vt, out, nullptr, nullptr, nullptr, nullptr, rowsum,
      S_, E_, S_, S_, B_ * S_, E_,
      (long)S_ * S_, (long)S_, (long)S_ * E_, 1.f, 16);
}